// Round 9
// baseline (57.343 us; speedup 1.0000x reference)
//
#include <hip/hip_runtime.h>
#include <hip/hip_fp16.h>
#include <math.h>

#define B_ 4
#define Q_ 1024
#define K_ 1024
#define DIN_ 256
#define H_ 64
#define DV_ 128
#define KT 64
#define GQ 4                 // queries per wave
#define MASKP -1000000.0f    // mask in log2 domain -> exp2 = 0
#define C2LOG2E 2.8853900817779268f   // 2*log2(e)
#define LOG2E 1.4426950408889634f

__device__ __forceinline__ float fexp2(float x) {
#if __has_builtin(__builtin_amdgcn_exp2f)
  return __builtin_amdgcn_exp2f(x);
#else
  return exp2f(x);
#endif
}
__device__ __forceinline__ float frcp(float x) {
#if __has_builtin(__builtin_amdgcn_rcpf)
  return __builtin_amdgcn_rcpf(x);
#else
  return 1.0f / x;
#endif
}

// blocks [0,512): row projections EQ/EK = exp2(C * row.W), 16 rows/block
// blocks [512,1024): values -> fp16 (packed pairs)
__global__ __launch_bounds__(256, 4) void prep_kernel(
    const float* __restrict__ queries, const float* __restrict__ keys,
    const float* __restrict__ values,
    const float* __restrict__ Wq, const float* __restrict__ Wk,
    float* __restrict__ eq, float* __restrict__ ek,
    unsigned short* __restrict__ vh) {
  int bid = blockIdx.x;
  int t = threadIdx.x;
  if (bid >= 512) {
    int i = ((bid - 512) * 256 + t) * 4;     // 512*256*4 = B*K*DV
    float4 v = *(const float4*)&values[i];
    ushort4 o;
    o.x = __half_as_ushort(__float2half(v.x));
    o.y = __half_as_ushort(__float2half(v.y));
    o.z = __half_as_ushort(__float2half(v.z));
    o.w = __half_as_ushort(__float2half(v.w));
    *(ushort4*)&vh[i] = o;
    return;
  }
  int w = t >> 6, lane = t & 63;
  int r0 = __builtin_amdgcn_readfirstlane(bid * 16 + w * 4);  // rows r0..r0+3
  const float* src;
  const float* W;
  float* dst;
  if (r0 < B_ * Q_) {
    src = queries + r0 * DIN_; W = Wq; dst = eq + r0 * H_;
  } else {
    int kr = r0 - B_ * Q_;
    src = keys + kr * DIN_; W = Wk; dst = ek + kr * H_;
  }
  float a00 = 0.f, a01 = 0.f, a10 = 0.f, a11 = 0.f;
  float a20 = 0.f, a21 = 0.f, a30 = 0.f, a31 = 0.f;
#pragma unroll 8
  for (int d = 0; d < DIN_; d += 2) {
    float w0 = W[d * H_ + lane];
    float w1 = W[(d + 1) * H_ + lane];
    a00 = fmaf(w0, src[d], a00);             a01 = fmaf(w1, src[d + 1], a01);
    a10 = fmaf(w0, src[DIN_ + d], a10);      a11 = fmaf(w1, src[DIN_ + d + 1], a11);
    a20 = fmaf(w0, src[2 * DIN_ + d], a20);  a21 = fmaf(w1, src[2 * DIN_ + d + 1], a21);
    a30 = fmaf(w0, src[3 * DIN_ + d], a30);  a31 = fmaf(w1, src[3 * DIN_ + d + 1], a31);
  }
  dst[lane]          = fexp2((a00 + a01) * C2LOG2E);
  dst[H_ + lane]     = fexp2((a10 + a11) * C2LOG2E);
  dst[2 * H_ + lane] = fexp2((a20 + a21) * C2LOG2E);
  dst[3 * H_ + lane] = fexp2((a30 + a31) * C2LOG2E);
}

// Flash attention over ONE K-split span, no max-tracking (scores bounded by
// sum|wv| -> exp2 fits fp32). Wave owns GQ=4 queries; lane owns 1 key slot.
// ek staged in LDS (shared by 4 waves); V read from global (L2-resident,
// coalesced). LDS ~21.5KB -> 7 blocks/CU; grid 256*ns blocks -> deep queue.
__global__ __launch_bounds__(256, 4) void attn_kernel(
    const float* __restrict__ eq, const float* __restrict__ ek,
    const unsigned* __restrict__ vh32, const float* __restrict__ wv,
    const int* __restrict__ vlen,
    float* __restrict__ pl, float* __restrict__ po,
    int ns, int span) {
  __shared__ __align__(16) float ek_s[KT][H_ + 4];   // pad 4: b128-clean
  __shared__ __align__(16) float p_s[4][GQ][KT];
  int t = threadIdx.x;
  int lane = t & 63;
  int w = t >> 6;
  int b = blockIdx.x >> 6;                    // 64 q-blocks (16 q) per batch
  int qt = blockIdx.x & 63;
  int s = blockIdx.y;
  int q0 = __builtin_amdgcn_readfirstlane(qt * 16 + w * GQ);
  int kv = vlen[b];
  int g = b * Q_ + q0;                        // queries g..g+3
  int k_lo = s * span;

  if (k_lo >= kv) {                           // inactive split: l=0 marker
    if (lane == 0) {
#pragma unroll
      for (int i = 0; i < GQ; ++i) pl[(g + i) * ns + s] = 0.f;
    }
    return;
  }

  const float* eq0 = eq + (size_t)g * H_;
  const float* eq1 = eq0 + H_;
  const float* eq2 = eq0 + 2 * H_;
  const float* eq3 = eq0 + 3 * H_;
  const float* ekb = ek + (size_t)b * K_ * H_;
  const unsigned* vbb = vh32 + (size_t)b * K_ * (DV_ / 2) + lane;

  // wsum = sum of w_v (butterfly; all lanes end with the total)
  float wsum = wv[lane];
#pragma unroll
  for (int sh = 32; sh >= 1; sh >>= 1) wsum += __shfl_xor(wsum, sh);
  float wl2 = wsum * LOG2E;
  const float nl2 = -2.0f * LOG2E;

  float l0 = 0.f, l1 = 0.f, l2 = 0.f, l3 = 0.f;
  float o0x = 0.f, o0y = 0.f, o1x = 0.f, o1y = 0.f;
  float o2x = 0.f, o2y = 0.f, o3x = 0.f, o3y = 0.f;

  int tile0 = k_lo >> 6;
  int tileE = min((kv + KT - 1) >> 6, (k_lo + span) >> 6);

  for (int tile = tile0; tile < tileE; ++tile) {
    int k0 = tile * KT;
    __syncthreads();                 // previous tile's readers done
    {
      const float4* gek = (const float4*)(ekb + (size_t)k0 * H_);
#pragma unroll
      for (int i = 0; i < 4; ++i) {
        int f4 = i * 256 + t;
        *(float4*)&ek_s[f4 >> 4][(f4 & 15) * 4] = gek[f4];
      }
    }
    __syncthreads();

    // scores, paired-h: w0/d0 + w1/d1 = (w0*d1 + w1*d0) / (d0*d1)
    const float* ekrow = ek_s[lane];
    float acc0 = 0.f, acc1 = 0.f, acc2 = 0.f, acc3 = 0.f;
#pragma unroll
    for (int hp = 0; hp < H_ / 2; ++hp) {
      int h = hp * 2;
      float ek0 = ekrow[h], ek1 = ekrow[h + 1];
      float w0 = wv[h], w1 = wv[h + 1];
      {
        float d0 = fmaf(eq0[h], ek0, 1.f), d1 = fmaf(eq0[h + 1], ek1, 1.f);
        float num = fmaf(w1, d0, w0 * d1);
        acc0 = fmaf(num, frcp(d0 * d1), acc0);
      }
      {
        float d0 = fmaf(eq1[h], ek0, 1.f), d1 = fmaf(eq1[h + 1], ek1, 1.f);
        float num = fmaf(w1, d0, w0 * d1);
        acc1 = fmaf(num, frcp(d0 * d1), acc1);
      }
      {
        float d0 = fmaf(eq2[h], ek0, 1.f), d1 = fmaf(eq2[h + 1], ek1, 1.f);
        float num = fmaf(w1, d0, w0 * d1);
        acc2 = fmaf(num, frcp(d0 * d1), acc2);
      }
      {
        float d0 = fmaf(eq3[h], ek0, 1.f), d1 = fmaf(eq3[h + 1], ek1, 1.f);
        float num = fmaf(w1, d0, w0 * d1);
        acc3 = fmaf(num, frcp(d0 * d1), acc3);
      }
    }
    // p = exp2(LOG2E*score); masked -> exp2(-1e6) = 0
    bool maskd = (k0 + lane) >= kv;
    float t0 = fmaf(nl2, acc0, wl2);
    float t1 = fmaf(nl2, acc1, wl2);
    float t2 = fmaf(nl2, acc2, wl2);
    float t3 = fmaf(nl2, acc3, wl2);
    if (maskd) { t0 = MASKP; t1 = MASKP; t2 = MASKP; t3 = MASKP; }
    float p0 = fexp2(t0), p1 = fexp2(t1), p2 = fexp2(t2), p3 = fexp2(t3);
    l0 += p0; l1 += p1; l2 += p2; l3 += p3;
    p_s[w][0][lane] = p0;
    p_s[w][1][lane] = p1;
    p_s[w][2][lane] = p2;
    p_s[w][3][lane] = p3;   // same-wave write->read, no barrier

    // PV: p broadcast from LDS (uniform addr), V fp16 pairs from global
#pragma unroll 4
    for (int k4 = 0; k4 < KT / 4; ++k4) {
      int kk = k4 * 4;
      float4 P0 = *(const float4*)&p_s[w][0][kk];
      float4 P1 = *(const float4*)&p_s[w][1][kk];
      float4 P2 = *(const float4*)&p_s[w][2][kk];
      float4 P3 = *(const float4*)&p_s[w][3][kk];
      size_t r = (size_t)(k0 + kk) * (DV_ / 2);
      unsigned u0 = vbb[r];
      unsigned u1 = vbb[r + (DV_ / 2)];
      unsigned u2 = vbb[r + 2 * (DV_ / 2)];
      unsigned u3 = vbb[r + 3 * (DV_ / 2)];
      __half2 h0 = *(__half2*)&u0, h1 = *(__half2*)&u1;
      __half2 h2 = *(__half2*)&u2, h3 = *(__half2*)&u3;
      float v0x = __low2float(h0), v0y = __high2float(h0);
      float v1x = __low2float(h1), v1y = __high2float(h1);
      float v2x = __low2float(h2), v2y = __high2float(h2);
      float v3x = __low2float(h3), v3y = __high2float(h3);
      o0x = fmaf(P0.x, v0x, o0x); o0y = fmaf(P0.x, v0y, o0y);
      o1x = fmaf(P1.x, v0x, o1x); o1y = fmaf(P1.x, v0y, o1y);
      o2x = fmaf(P2.x, v0x, o2x); o2y = fmaf(P2.x, v0y, o2y);
      o3x = fmaf(P3.x, v0x, o3x); o3y = fmaf(P3.x, v0y, o3y);
      o0x = fmaf(P0.y, v1x, o0x); o0y = fmaf(P0.y, v1y, o0y);
      o1x = fmaf(P1.y, v1x, o1x); o1y = fmaf(P1.y, v1y, o1y);
      o2x = fmaf(P2.y, v1x, o2x); o2y = fmaf(P2.y, v1y, o2y);
      o3x = fmaf(P3.y, v1x, o3x); o3y = fmaf(P3.y, v1y, o3y);
      o0x = fmaf(P0.z, v2x, o0x); o0y = fmaf(P0.z, v2y, o0y);
      o1x = fmaf(P1.z, v2x, o1x); o1y = fmaf(P1.z, v2y, o1y);
      o2x = fmaf(P2.z, v2x, o2x); o2y = fmaf(P2.z, v2y, o2y);
      o3x = fmaf(P3.z, v2x, o3x); o3y = fmaf(P3.z, v2y, o3y);
      o0x = fmaf(P0.w, v3x, o0x); o0y = fmaf(P0.w, v3y, o0y);
      o1x = fmaf(P1.w, v3x, o1x); o1y = fmaf(P1.w, v3y, o1y);
      o2x = fmaf(P2.w, v3x, o2x); o2y = fmaf(P2.w, v3y, o2y);
      o3x = fmaf(P3.w, v3x, o3x); o3y = fmaf(P3.w, v3y, o3y);
    }
  }

  // l: one reduce per split (not per tile)
#pragma unroll
  for (int sh = 32; sh >= 1; sh >>= 1) {
    l0 += __shfl_xor(l0, sh);
    l1 += __shfl_xor(l1, sh);
    l2 += __shfl_xor(l2, sh);
    l3 += __shfl_xor(l3, sh);
  }
  if (lane == 0) {
    pl[(g + 0) * ns + s] = l0;
    pl[(g + 1) * ns + s] = l1;
    pl[(g + 2) * ns + s] = l2;
    pl[(g + 3) * ns + s] = l3;
  }
  size_t pb = ((size_t)g * ns + s) * DV_ + lane * 2;
  *(float2*)&po[pb] = make_float2(o0x, o0y);
  *(float2*)&po[pb + (size_t)ns * DV_] = make_float2(o1x, o1y);
  *(float2*)&po[pb + (size_t)2 * ns * DV_] = make_float2(o2x, o2y);
  *(float2*)&po[pb + (size_t)3 * ns * DV_] = make_float2(o3x, o3y);
}

// out = (sum_s o_s) / (sum_s l_s); skip l==0 splits (po unwritten there)
__global__ __launch_bounds__(256, 4) void combine_kernel(
    const float* __restrict__ pl, const float* __restrict__ po,
    float* __restrict__ out, int ns) {
  int t = threadIdx.x;
  int lane = t & 63;
  int w = t >> 6;
  int g = blockIdx.x * 4 + w;
  float L = 0.f, ax = 0.f, ay = 0.f;
  for (int s = 0; s < ns; ++s) {
    float ls = pl[g * ns + s];
    if (ls != 0.f) {                 // wave-uniform
      L += ls;
      float2 o2 = *(const float2*)&po[((size_t)g * ns + s) * DV_ + lane * 2];
      ax += o2.x;
      ay += o2.y;
    }
  }
  float inv = frcp(L);
  *(float2*)&out[(size_t)g * DV_ + lane * 2] = make_float2(ax * inv, ay * inv);
}

extern "C" void kernel_launch(void* const* d_in, const int* in_sizes, int n_in,
                              void* d_out, int out_size, void* d_ws, size_t ws_size,
                              hipStream_t stream) {
  const float* queries = (const float*)d_in[0];
  const float* keys    = (const float*)d_in[1];
  const float* values  = (const float*)d_in[2];
  const int*   vl      = (const int*)d_in[3];
  const float* Wq      = (const float*)d_in[4];
  const float* Wk      = (const float*)d_in[5];
  const float* wv      = (const float*)d_in[6];
  float* out = (float*)d_out;

  float* eq = (float*)d_ws;                              // 1 MB
  float* ek = eq + (size_t)B_ * Q_ * H_;                 // 1 MB
  unsigned short* vh = (unsigned short*)(ek + (size_t)B_ * K_ * H_);  // 1 MB
  char* dyn = (char*)(vh + (size_t)B_ * K_ * DV_);
  size_t fixed = (size_t)(dyn - (char*)d_ws);

  // choose K-split count by available workspace (deterministic per session)
  int ns = 2;
  for (int cand = 8; cand >= 2; cand >>= 1) {
    size_t need = fixed + (size_t)B_ * Q_ * cand * 4            // pl
                + (size_t)B_ * Q_ * cand * DV_ * 4;             // po
    if (ws_size >= need) { ns = cand; break; }
  }
  int span = K_ / ns;
  float* pl = (float*)dyn;
  float* po = pl + (size_t)B_ * Q_ * ns;

  prep_kernel<<<dim3(1024), dim3(256), 0, stream>>>(
      queries, keys, values, Wq, Wk, eq, ek, vh);
  attn_kernel<<<dim3(B_ * (Q_ / 16), ns), dim3(256), 0, stream>>>(
      eq, ek, (const unsigned*)vh, wv, vl, pl, po, ns, span);
  combine_kernel<<<dim3(B_ * Q_ / 4), dim3(256), 0, stream>>>(pl, po, out, ns);
}

// Round 10
// 40.422 us; speedup vs baseline: 1.4186x; 1.4186x over previous
//
#include <hip/hip_runtime.h>
#include <hip/hip_fp16.h>
#include <math.h>

#define B_ 4
#define Q_ 1024
#define K_ 1024
#define DIN_ 256
#define H_ 64
#define DV_ 128
#define KT 64
#define MASKP -1000000.0f    // mask in log2 domain -> exp2 = 0
#define C2LOG2E 2.8853900817779268f   // 2*log2(e)
#define LOG2E 1.4426950408889634f

__device__ __forceinline__ float fexp2(float x) {
#if __has_builtin(__builtin_amdgcn_exp2f)
  return __builtin_amdgcn_exp2f(x);
#else
  return exp2f(x);
#endif
}
__device__ __forceinline__ float frcp(float x) {
#if __has_builtin(__builtin_amdgcn_rcpf)
  return __builtin_amdgcn_rcpf(x);
#else
  return 1.0f / x;
#endif
}

// blocks [0,512): row projections EQ/EK = exp2(C * row.W), 16 rows/block
// blocks [512,1024): values -> fp16 (packed pairs)
__global__ __launch_bounds__(256, 4) void prep_kernel(
    const float* __restrict__ queries, const float* __restrict__ keys,
    const float* __restrict__ values,
    const float* __restrict__ Wq, const float* __restrict__ Wk,
    float* __restrict__ eq, float* __restrict__ ek,
    unsigned short* __restrict__ vh) {
  int bid = blockIdx.x;
  int t = threadIdx.x;
  if (bid >= 512) {
    int i = ((bid - 512) * 256 + t) * 4;     // 512*256*4 = B*K*DV
    float4 v = *(const float4*)&values[i];
    ushort4 o;
    o.x = __half_as_ushort(__float2half(v.x));
    o.y = __half_as_ushort(__float2half(v.y));
    o.z = __half_as_ushort(__float2half(v.z));
    o.w = __half_as_ushort(__float2half(v.w));
    *(ushort4*)&vh[i] = o;
    return;
  }
  int w = t >> 6, lane = t & 63;
  int r0 = __builtin_amdgcn_readfirstlane(bid * 16 + w * 4);  // rows r0..r0+3
  const float* src;
  const float* W;
  float* dst;
  if (r0 < B_ * Q_) {
    src = queries + r0 * DIN_; W = Wq; dst = eq + r0 * H_;
  } else {
    int kr = r0 - B_ * Q_;
    src = keys + kr * DIN_; W = Wk; dst = ek + kr * H_;
  }
  float a00 = 0.f, a01 = 0.f, a10 = 0.f, a11 = 0.f;
  float a20 = 0.f, a21 = 0.f, a30 = 0.f, a31 = 0.f;
#pragma unroll 8
  for (int d = 0; d < DIN_; d += 2) {
    float w0 = W[d * H_ + lane];
    float w1 = W[(d + 1) * H_ + lane];
    a00 = fmaf(w0, src[d], a00);             a01 = fmaf(w1, src[d + 1], a01);
    a10 = fmaf(w0, src[DIN_ + d], a10);      a11 = fmaf(w1, src[DIN_ + d + 1], a11);
    a20 = fmaf(w0, src[2 * DIN_ + d], a20);  a21 = fmaf(w1, src[2 * DIN_ + d + 1], a21);
    a30 = fmaf(w0, src[3 * DIN_ + d], a30);  a31 = fmaf(w1, src[3 * DIN_ + d + 1], a31);
  }
  dst[lane]          = fexp2((a00 + a01) * C2LOG2E);
  dst[H_ + lane]     = fexp2((a10 + a11) * C2LOG2E);
  dst[2 * H_ + lane] = fexp2((a20 + a21) * C2LOG2E);
  dst[3 * H_ + lane] = fexp2((a30 + a31) * C2LOG2E);
}

// Flash attention over ONE K-split span, no max-tracking (scores bounded by
// sum|wv| ~ 6.4 -> exp2 fits fp32). Wave owns 2 queries; lane owns 1 key.
// ALL in-loop operands are LDS-resident (ek per-lane; eq/wv uniform-addr
// broadcast) -> no s_load in the loop -> no lgkmcnt(0) SMEM drains, DS pipe
// stays pipelined. V fp16 in LDS (shared by 4 waves).
__global__ __launch_bounds__(256, 4) void attn_kernel(
    const float* __restrict__ eq, const float* __restrict__ ek,
    const unsigned* __restrict__ vh32, const float* __restrict__ wv,
    const int* __restrict__ vlen,
    float* __restrict__ pl, float* __restrict__ po,
    int ns, int span) {
  __shared__ __align__(16) float ek_s[KT][H_ + 4];     // pad 4: b128-clean
  __shared__ __align__(16) unsigned v_s[KT][DV_ / 2];  // fp16 pairs
  __shared__ __align__(16) float p_s[4][2][KT];
  __shared__ float4 eq4_s[8 * 16];                     // [q][h4], 8 q/block
  __shared__ float4 wv4_s[16];
  int t = threadIdx.x;
  int lane = t & 63;
  int w = t >> 6;
  int b = blockIdx.x >> 7;                    // 128 q-blocks (8 q) per batch
  int qt = blockIdx.x & 127;
  int s = blockIdx.y;
  int q0 = __builtin_amdgcn_readfirstlane(qt * 8 + w * 2);
  int kv = vlen[b];
  int g = b * Q_ + q0;                        // queries g, g+1
  int k_lo = s * span;

  if (k_lo >= kv) {                           // inactive split: l=0 marker
    if (lane == 0) {
      pl[(g + 0) * ns + s] = 0.f;
      pl[(g + 1) * ns + s] = 0.f;
    }
    return;
  }

  const float* ekb = ek + (size_t)b * K_ * H_;
  const unsigned* vgb = vh32 + (size_t)b * K_ * (DV_ / 2);

  // stage eq (block's 8 query rows) and wv into LDS; visible after the
  // first in-loop barrier.
  if (t < 128)
    eq4_s[t] = ((const float4*)(eq + (size_t)(b * Q_ + qt * 8) * H_))[t];
  if (t < 16) wv4_s[t] = ((const float4*)wv)[t];

  // wsum = sum of w_v (butterfly; all lanes end with the total)
  float wsum = wv[lane];
#pragma unroll
  for (int sh = 32; sh >= 1; sh >>= 1) wsum += __shfl_xor(wsum, sh);
  float wl2 = wsum * LOG2E;
  const float nl2 = -2.0f * LOG2E;

  float l0 = 0.f, l1 = 0.f;
  float o0x = 0.f, o0y = 0.f, o1x = 0.f, o1y = 0.f;

  int tile0 = k_lo >> 6;
  int tileE = min((kv + KT - 1) >> 6, (k_lo + span) >> 6);
  const float4* e4a = &eq4_s[(w * 2 + 0) * 16];
  const float4* e4b = &eq4_s[(w * 2 + 1) * 16];

  for (int tile = tile0; tile < tileE; ++tile) {
    int k0 = tile * KT;
    __syncthreads();                 // prior readers done (+ eq_s visible)
    {
      const float4* gek = (const float4*)(ekb + (size_t)k0 * H_);
      const float4* gv = (const float4*)(vgb + (size_t)k0 * (DV_ / 2));
#pragma unroll
      for (int i = 0; i < 4; ++i) {
        int f4 = i * 256 + t;
        *(float4*)&ek_s[f4 >> 4][(f4 & 15) * 4] = gek[f4];
      }
#pragma unroll
      for (int i = 0; i < 4; ++i) {
        int f4 = i * 256 + t;
        *(float4*)&v_s[f4 >> 4][(f4 & 15) * 4] = gv[f4];
      }
    }
    __syncthreads();

    // scores, paired-h: w0/d0 + w1/d1 = (w0*d1 + w1*d0) / (d0*d1)
    float acc0 = 0.f, acc1 = 0.f;
#pragma unroll
    for (int h4 = 0; h4 < 16; ++h4) {
      float4 ekv = *(const float4*)&ek_s[lane][h4 * 4];
      float4 wq = wv4_s[h4];
      float4 ea = e4a[h4];
      float4 eb = e4b[h4];
      {
        float d0 = fmaf(ea.x, ekv.x, 1.f), d1 = fmaf(ea.y, ekv.y, 1.f);
        acc0 = fmaf(fmaf(wq.y, d0, wq.x * d1), frcp(d0 * d1), acc0);
        float d2 = fmaf(ea.z, ekv.z, 1.f), d3 = fmaf(ea.w, ekv.w, 1.f);
        acc0 = fmaf(fmaf(wq.w, d2, wq.z * d3), frcp(d2 * d3), acc0);
      }
      {
        float d0 = fmaf(eb.x, ekv.x, 1.f), d1 = fmaf(eb.y, ekv.y, 1.f);
        acc1 = fmaf(fmaf(wq.y, d0, wq.x * d1), frcp(d0 * d1), acc1);
        float d2 = fmaf(eb.z, ekv.z, 1.f), d3 = fmaf(eb.w, ekv.w, 1.f);
        acc1 = fmaf(fmaf(wq.w, d2, wq.z * d3), frcp(d2 * d3), acc1);
      }
    }
    // p = exp2(LOG2E*score); masked -> exp2(-1e6) = 0
    bool maskd = (k0 + lane) >= kv;
    float t0 = fmaf(nl2, acc0, wl2);
    float t1 = fmaf(nl2, acc1, wl2);
    if (maskd) { t0 = MASKP; t1 = MASKP; }
    float p0 = fexp2(t0), p1 = fexp2(t1);
    l0 += p0; l1 += p1;
    p_s[w][0][lane] = p0;
    p_s[w][1][lane] = p1;            // same-wave write->read, no barrier

    // PV: p broadcast (uniform addr), V fp16 pairs per-lane from LDS
#pragma unroll 8
    for (int k4 = 0; k4 < KT / 4; ++k4) {
      int kk = k4 * 4;
      float4 P0 = *(const float4*)&p_s[w][0][kk];
      float4 P1 = *(const float4*)&p_s[w][1][kk];
      unsigned u0 = v_s[kk][lane];
      unsigned u1 = v_s[kk + 1][lane];
      unsigned u2 = v_s[kk + 2][lane];
      unsigned u3 = v_s[kk + 3][lane];
      __half2 h0 = *(__half2*)&u0, h1 = *(__half2*)&u1;
      __half2 h2 = *(__half2*)&u2, h3 = *(__half2*)&u3;
      float v0x = __low2float(h0), v0y = __high2float(h0);
      float v1x = __low2float(h1), v1y = __high2float(h1);
      float v2x = __low2float(h2), v2y = __high2float(h2);
      float v3x = __low2float(h3), v3y = __high2float(h3);
      o0x = fmaf(P0.x, v0x, o0x); o0y = fmaf(P0.x, v0y, o0y);
      o1x = fmaf(P1.x, v0x, o1x); o1y = fmaf(P1.x, v0y, o1y);
      o0x = fmaf(P0.y, v1x, o0x); o0y = fmaf(P0.y, v1y, o0y);
      o1x = fmaf(P1.y, v1x, o1x); o1y = fmaf(P1.y, v1y, o1y);
      o0x = fmaf(P0.z, v2x, o0x); o0y = fmaf(P0.z, v2y, o0y);
      o1x = fmaf(P1.z, v2x, o1x); o1y = fmaf(P1.z, v2y, o1y);
      o0x = fmaf(P0.w, v3x, o0x); o0y = fmaf(P0.w, v3y, o0y);
      o1x = fmaf(P1.w, v3x, o1x); o1y = fmaf(P1.w, v3y, o1y);
    }
  }

  // l: one reduce per split (not per tile)
#pragma unroll
  for (int sh = 32; sh >= 1; sh >>= 1) {
    l0 += __shfl_xor(l0, sh);
    l1 += __shfl_xor(l1, sh);
  }
  if (lane == 0) {
    pl[(g + 0) * ns + s] = l0;
    pl[(g + 1) * ns + s] = l1;
  }
  size_t pb = ((size_t)g * ns + s) * DV_ + lane * 2;
  *(float2*)&po[pb] = make_float2(o0x, o0y);
  *(float2*)&po[pb + (size_t)ns * DV_] = make_float2(o1x, o1y);
}

// out = (sum_s o_s) / (sum_s l_s); skip l==0 splits (po unwritten there)
__global__ __launch_bounds__(256, 4) void combine_kernel(
    const float* __restrict__ pl, const float* __restrict__ po,
    float* __restrict__ out, int ns) {
  int t = threadIdx.x;
  int lane = t & 63;
  int w = t >> 6;
  int g = blockIdx.x * 4 + w;
  float L = 0.f, ax = 0.f, ay = 0.f;
  for (int s = 0; s < ns; ++s) {
    float ls = pl[g * ns + s];
    if (ls != 0.f) {                 // wave-uniform
      L += ls;
      float2 o2 = *(const float2*)&po[((size_t)g * ns + s) * DV_ + lane * 2];
      ax += o2.x;
      ay += o2.y;
    }
  }
  float inv = frcp(L);
  *(float2*)&out[(size_t)g * DV_ + lane * 2] = make_float2(ax * inv, ay * inv);
}

extern "C" void kernel_launch(void* const* d_in, const int* in_sizes, int n_in,
                              void* d_out, int out_size, void* d_ws, size_t ws_size,
                              hipStream_t stream) {
  const float* queries = (const float*)d_in[0];
  const float* keys    = (const float*)d_in[1];
  const float* values  = (const float*)d_in[2];
  const int*   vl      = (const int*)d_in[3];
  const float* Wq      = (const float*)d_in[4];
  const float* Wk      = (const float*)d_in[5];
  const float* wv      = (const float*)d_in[6];
  float* out = (float*)d_out;

  float* eq = (float*)d_ws;                              // 1 MB
  float* ek = eq + (size_t)B_ * Q_ * H_;                 // 1 MB
  unsigned short* vh = (unsigned short*)(ek + (size_t)B_ * K_ * H_);  // 1 MB
  char* dyn = (char*)(vh + (size_t)B_ * K_ * DV_);
  size_t fixed = (size_t)(dyn - (char*)d_ws);

  // choose K-split count by available workspace (deterministic per session)
  int ns = 2;
  for (int cand = 8; cand >= 2; cand >>= 1) {
    size_t need = fixed + (size_t)B_ * Q_ * cand * 4            // pl
                + (size_t)B_ * Q_ * cand * DV_ * 4;             // po
    if (ws_size >= need) { ns = cand; break; }
  }
  int span = K_ / ns;
  float* pl = (float*)dyn;
  float* po = pl + (size_t)B_ * Q_ * ns;

  prep_kernel<<<dim3(1024), dim3(256), 0, stream>>>(
      queries, keys, values, Wq, Wk, eq, ek, vh);
  attn_kernel<<<dim3(B_ * (Q_ / 8), ns), dim3(256), 0, stream>>>(
      eq, ek, (const unsigned*)vh, wv, vl, pl, po, ns, span);
  combine_kernel<<<dim3(B_ * Q_ / 4), dim3(256), 0, stream>>>(pl, po, out, ns);
}